// Round 1
// 991.750 us; speedup vs baseline: 1.0847x; 1.0847x over previous
//
#include <hip/hip_runtime.h>
#include <cstdint>

#define NN 8192
#define DD 256
#define KS 4   // k-splits for the dense levels

typedef unsigned short u16;
typedef __bf16 bf16x8 __attribute__((ext_vector_type(8)));
typedef float f32x4 __attribute__((ext_vector_type(4)));

__device__ __forceinline__ u16 f2bf(float f) {
    union { float f; unsigned u; } c; c.f = f;
    unsigned u = c.u;
    return (u16)((u + 0x7FFFu + ((u >> 16) & 1u)) >> 16);   // RNE
}

// ---------------------------------------------------------------------------
// GEMM: C[M x 256] = A[M x K] * B[K x 256], B given transposed (BT[n][k], bf16).
// A fp32 (AF32=1, converted in-kernel) or bf16 (AF32=0).
// Tile 64(m) x 256(n) x 32(k-step); 4 waves; wave w owns n in [64w, 64w+64);
// each wave 4x4 frags of mfma_f32_16x16x32_bf16. grid=(M/64, 1, KSPLIT).
// Split-K: block z writes its own slab C + z*NN*DD (no atomics); reduction is
// fused into the norm kernels. ROWSUM: wave 0 accumulates rowsum(A-tile) via
// ones-column B fragment, written per-slab to rs + z*NN.
// ---------------------------------------------------------------------------
template<bool AF32, bool ROWSUM>
__global__ __launch_bounds__(256, 2)
void gemm_k(const void* __restrict__ Ap, long ldA,
            const u16* __restrict__ BT, long ldBT,
            float* __restrict__ C, float* __restrict__ rs, int kPer)
{
    __shared__ __align__(16) u16 As[64 * 32];     // 4 groups of 16 rows
    __shared__ __align__(16) u16 Bs[256 * 32];    // 16 groups

    const int tid  = threadIdx.x;
    const int lane = tid & 63;
    const int wave = tid >> 6;       // 0..3
    const int r    = lane & 15;
    const int q    = lane >> 4;
    const long m0  = (long)blockIdx.x * 64;
    const long k0  = (long)blockIdx.z * kPer;
    float* __restrict__ Cs = C + (long)blockIdx.z * ((long)NN * DD);

    f32x4 acc[4][4] = {};
    f32x4 racc[4]   = {};
    bf16x8 ones;
    if constexpr (ROWSUM) {
        union { bf16x8 v; u16 u[8]; } cv;
        u16 pat = (r == 0) ? (u16)0x3F80 : (u16)0;   // 1.0 in n-col 0
        #pragma unroll
        for (int j = 0; j < 8; ++j) cv.u[j] = pat;
        ones = cv.v;
    }

    // B staging: wave loads groups 4w..4w+3 (rows wave*64 + g2*16 + r)
    const u16* bBase = BT + (long)(wave * 64 + r) * ldBT + k0 + q * 8;
    // A staging (AF32): thread t handles row t>>2, k-octet t&3 (8 fp32 -> 8 bf16)
    const int arow = tid >> 2;
    const int kq8  = tid & 3;
    const float* aBaseF = AF32 ? ((const float*)Ap + (m0 + arow) * ldA + k0 + kq8 * 8) : nullptr;
    // A staging (bf16): wave loads group `wave` via global_load_lds
    const u16* aBaseH = AF32 ? nullptr
                             : ((const u16*)Ap + (m0 + wave * 16 + r) * ldA + k0 + q * 8);
    const int nsteps = kPer >> 5;

    for (int s = 0; s < nsteps; ++s) {
        const long koff = (long)s << 5;
        if constexpr (AF32) {
            const float* ap = aBaseF + koff;
            // A is streamed exactly once: non-temporal to keep L2/LLC for B/C
            f32x4 f0 = __builtin_nontemporal_load((const f32x4*)ap);
            f32x4 f1 = __builtin_nontemporal_load((const f32x4*)(ap + 4));
            union { u16 u[8]; uint4 v; } pk;
            pk.u[0] = f2bf(f0[0]); pk.u[1] = f2bf(f0[1]);
            pk.u[2] = f2bf(f0[2]); pk.u[3] = f2bf(f0[3]);
            pk.u[4] = f2bf(f1[0]); pk.u[5] = f2bf(f1[1]);
            pk.u[6] = f2bf(f1[2]); pk.u[7] = f2bf(f1[3]);
            // chunk: group g=arow>>4, slot l = kq8*16 + (arow&15)
            *(uint4*)(As + (arow >> 4) * 512 + (kq8 * 16 + (arow & 15)) * 8) = pk.v;
        } else {
            __builtin_amdgcn_global_load_lds(
                (const __attribute__((address_space(1))) void*)(aBaseH + koff),
                (__attribute__((address_space(3))) void*)(As + wave * 512 + lane * 8),
                16, 0, 0);
        }
        #pragma unroll
        for (int g2 = 0; g2 < 4; ++g2) {
            __builtin_amdgcn_global_load_lds(
                (const __attribute__((address_space(1))) void*)(bBase + (long)g2 * 16 * ldBT + koff),
                (__attribute__((address_space(3))) void*)(Bs + (wave * 4 + g2) * 512 + lane * 8),
                16, 0, 0);
        }
        __syncthreads();

        bf16x8 af[4], bfr[4];
        #pragma unroll
        for (int i = 0; i < 4; ++i) {
            af[i]  = *(const bf16x8*)(As + i * 512 + lane * 8);
            bfr[i] = *(const bf16x8*)(Bs + (wave * 4 + i) * 512 + lane * 8);
        }
        #pragma unroll
        for (int i = 0; i < 4; ++i)
            #pragma unroll
            for (int j = 0; j < 4; ++j)
                acc[i][j] = __builtin_amdgcn_mfma_f32_16x16x32_bf16(af[i], bfr[j], acc[i][j], 0, 0, 0);
        if constexpr (ROWSUM) {
            if (wave == 0) {
                #pragma unroll
                for (int i = 0; i < 4; ++i)
                    racc[i] = __builtin_amdgcn_mfma_f32_16x16x32_bf16(af[i], ones, racc[i], 0, 0, 0);
            }
        }
        __syncthreads();
    }

    // epilogue: C/D layout col = lane&15, row = (lane>>4)*4 + reg
    #pragma unroll
    for (int i = 0; i < 4; ++i) {
        const long rowb = m0 + i * 16 + q * 4;
        #pragma unroll
        for (int j = 0; j < 4; ++j) {
            const long col = wave * 64 + j * 16 + r;
            #pragma unroll
            for (int rr2 = 0; rr2 < 4; ++rr2)
                Cs[(rowb + rr2) * DD + col] = acc[i][j][rr2];
        }
        if constexpr (ROWSUM) {
            if (wave == 0 && r == 0) {
                #pragma unroll
                for (int rr2 = 0; rr2 < 4; ++rr2)
                    rs[(long)blockIdx.z * NN + rowb + rr2] = racc[i][rr2];
            }
        }
    }
}

// ---------------------------------------------------------------------------
// transpose-convert: src fp32 [R][C] -> dst bf16 [C][R]. 64x64 tiles.
// ---------------------------------------------------------------------------
__global__ __launch_bounds__(256)
void tc_k(const float* __restrict__ src, u16* __restrict__ dst, int R, int C)
{
    __shared__ u16 t[64][72];
    const int tid = threadIdx.x;
    const int rr = tid >> 2;
    const int cc = (tid & 3) << 4;
    const long r0 = (long)blockIdx.x * 64;
    const long c0 = (long)blockIdx.y * 64;
    const float* sp = src + (r0 + rr) * C + c0 + cc;
    #pragma unroll
    for (int j = 0; j < 16; ++j) t[cc + j][rr] = f2bf(sp[j]);
    __syncthreads();
    u16* dp = dst + (c0 + rr) * (long)R + r0 + cc;
    #pragma unroll
    for (int j = 0; j < 16; ++j) dp[j] = t[rr][cc + j];
}

// ---------------------------------------------------------------------------
// norm0: v = (resid + sum_s Cacc[s]) * 1/(sum_s rs[s]+1); write outF fp32
// [N][256] AND outT bf16 [256][N] (transposed). 64x64 tiles.
// ---------------------------------------------------------------------------
__global__ __launch_bounds__(256)
void norm0_k(const float* __restrict__ Cacc, const float* __restrict__ rs,
             const float* __restrict__ resid,
             float* __restrict__ outF, u16* __restrict__ outT)
{
    __shared__ u16 t[64][72];
    const int tid = threadIdx.x;
    const int rr = tid >> 2;
    const int cc = (tid & 3) << 4;
    const long i0 = (long)blockIdx.x * 64;
    const int  n0 = blockIdx.y * 64;
    const long i  = i0 + rr;
    const float rsum = rs[i] + rs[NN + i] + rs[2 * NN + i] + rs[3 * NN + i];
    const float scale = 1.0f / (rsum + 1.0f);
    const float* c0p = Cacc + i * DD + n0 + cc;
    const float* rp  = resid + i * DD + n0 + cc;
    float* fp = outF + i * DD + n0 + cc;
    const long slab = (long)NN * DD;
    #pragma unroll
    for (int j = 0; j < 16; ++j) {
        float v = rp[j] + c0p[j] + c0p[j + slab] + c0p[j + 2 * slab] + c0p[j + 3 * slab];
        v *= scale;
        fp[j] = v;
        t[cc + j][rr] = f2bf(v);
    }
    __syncthreads();
    u16* op = outT + (long)(n0 + rr) * NN + i0 + cc;
    #pragma unroll
    for (int j = 0; j < 16; ++j) op[j] = t[rr][cc + j];
}

// ---------------------------------------------------------------------------
// norm1: v = (resid + sum_s Cacc[s]) * 1/(sum_s rs[s]+1); write bf16 row-major
// [N][256]. grid 2048 x 256thr, 4 elems/thread.
// ---------------------------------------------------------------------------
__global__ __launch_bounds__(256)
void norm1_k(const float* __restrict__ Cacc, const float* __restrict__ rs,
             const float* __restrict__ resid, u16* __restrict__ outR)
{
    const long g = ((long)blockIdx.x * 256 + threadIdx.x) * 4;
    const long row = g >> 8;
    const float rsum = rs[row] + rs[NN + row] + rs[2 * NN + row] + rs[3 * NN + row];
    const float scale = 1.0f / (rsum + 1.0f);
    const long slab = (long)NN * DD;
    const float4 c0 = *(const float4*)(Cacc + g);
    const float4 c1 = *(const float4*)(Cacc + g + slab);
    const float4 c2 = *(const float4*)(Cacc + g + 2 * slab);
    const float4 c3 = *(const float4*)(Cacc + g + 3 * slab);
    const float4 rv = *(const float4*)(resid + g);
    u16* op = outR + g;
    op[0] = f2bf((rv.x + c0.x + c1.x + c2.x + c3.x) * scale);
    op[1] = f2bf((rv.y + c0.y + c1.y + c2.y + c3.y) * scale);
    op[2] = f2bf((rv.z + c0.z + c1.z + c2.z + c3.z) * scale);
    op[3] = f2bf((rv.w + c0.w + c1.w + c2.w + c3.w) * scale);
}

// ---------------------------------------------------------------------------
// GCN helpers
// ---------------------------------------------------------------------------
__global__ __launch_bounds__(256)
void count_k(const int* __restrict__ dst, int E, int* __restrict__ counts) {
    int e = blockIdx.x * 256 + threadIdx.x;
    if (e < E) atomicAdd(counts + dst[e], 1);
}

// exclusive scan of 8192 counts: 1024 threads, wave-shuffle scan (3 barriers
// per 1024-chunk instead of the old 640-barrier Hillis-Steele).
__global__ __launch_bounds__(1024)
void scan_k(const int* __restrict__ counts, int* __restrict__ offs,
            int* __restrict__ cursor, float* __restrict__ dinv) {
    __shared__ int wpre[17];
    __shared__ int sbase;
    const int tid  = threadIdx.x;
    const int lane = tid & 63;
    const int wid  = tid >> 6;          // 0..15
    if (tid == 0) { sbase = 0; wpre[0] = 0; }
    __syncthreads();
    for (int base = 0; base < NN; base += 1024) {
        const int c = counts[base + tid];
        dinv[base + tid] = 1.0f / sqrtf((float)c + 1.0f);
        int x = c;                       // inclusive wave scan
        #pragma unroll
        for (int d = 1; d < 64; d <<= 1) {
            int y = __shfl_up(x, d, 64);
            if (lane >= d) x += y;
        }
        if (lane == 63) wpre[wid + 1] = x;
        __syncthreads();
        if (wid == 0) {                  // scan the 16 wave sums
            int w = (lane < 16) ? wpre[lane + 1] : 0;
            #pragma unroll
            for (int d = 1; d < 16; d <<= 1) {
                int y = __shfl_up(w, d, 64);
                if (lane >= d) w += y;
            }
            if (lane < 16) wpre[lane + 1] = w;
        }
        __syncthreads();
        const int excl = sbase + wpre[wid] + (x - c);
        offs[base + tid]   = excl;
        cursor[base + tid] = excl;
        __syncthreads();                 // all reads of sbase/wpre done
        if (tid == 0) sbase += wpre[16]; // visible after next barrier
    }
    if (tid == 0) offs[NN] = sbase;
}

__global__ __launch_bounds__(256)
void fill_k(const int* __restrict__ src, const int* __restrict__ dst, int E,
            int* __restrict__ cursor, int* __restrict__ csr) {
    int e = blockIdx.x * 256 + threadIdx.x;
    if (e < E) {
        int p = atomicAdd(cursor + dst[e], 1);
        csr[p] = src[e];
    }
}

// ---------------------------------------------------------------------------
// gather: out[i] = b + dinv[i]^2*h[i] + sum_{e:dst=i} dinv[i]*dinv[src]*h[src]
// one wave per node, lane owns 4 features; 2-deep edge pipeline.
// ---------------------------------------------------------------------------
__global__ __launch_bounds__(256)
void gather_k(const float* __restrict__ h,
              const int* __restrict__ offs,
              const int* __restrict__ csr,
              const float* __restrict__ dinv,
              const float* __restrict__ bias,
              u16* __restrict__ outBF,
              float* __restrict__ outF)
{
    const int node = blockIdx.x * 4 + (threadIdx.x >> 6);
    const int lane = threadIdx.x & 63;
    const float di = dinv[node];
    const float4 hs = ((const float4*)(h + (long)node * DD))[lane];
    const float s0 = di * di;
    float4 acc;
    acc.x = hs.x * s0; acc.y = hs.y * s0; acc.z = hs.z * s0; acc.w = hs.w * s0;

    const int b0 = offs[node], b1 = offs[node + 1];
    int e = b0;
    for (; e + 2 <= b1; e += 2) {
        const int sa = csr[e], sb = csr[e + 1];
        const float wa = di * dinv[sa];
        const float wb = di * dinv[sb];
        const float4 xa = ((const float4*)(h + (long)sa * DD))[lane];
        const float4 xb = ((const float4*)(h + (long)sb * DD))[lane];
        acc.x += wa * xa.x + wb * xb.x;
        acc.y += wa * xa.y + wb * xb.y;
        acc.z += wa * xa.z + wb * xb.z;
        acc.w += wa * xa.w + wb * xb.w;
    }
    if (e < b1) {
        const int s = csr[e];
        const float w = di * dinv[s];
        const float4 x = ((const float4*)(h + (long)s * DD))[lane];
        acc.x += w * x.x; acc.y += w * x.y; acc.z += w * x.z; acc.w += w * x.w;
    }
    const float4 bv = ((const float4*)bias)[lane];
    acc.x += bv.x; acc.y += bv.y; acc.z += bv.z; acc.w += bv.w;

    if (outF) {
        ((float4*)(outF + (long)node * DD))[lane] = acc;
    } else {
        u16* op = outBF + (long)node * DD + lane * 4;
        op[0] = f2bf(acc.x); op[1] = f2bf(acc.y);
        op[2] = f2bf(acc.z); op[3] = f2bf(acc.w);
    }
}

// ---------------------------------------------------------------------------
extern "C" void kernel_launch(void* const* d_in, const int* in_sizes, int n_in,
                              void* d_out, int out_size, void* d_ws, size_t ws_size,
                              hipStream_t stream)
{
    (void)n_in; (void)out_size; (void)ws_size;
    const float* emb0  = (const float*)d_in[0];
    const float* A     = (const float*)d_in[1];
    const int*   eiS   = (const int*)d_in[2];
    const int*   eiU   = (const int*)d_in[3];
    const float* Wsame = (const float*)d_in[4];
    const float* bsame = (const float*)d_in[5];
    const float* Wtop  = (const float*)d_in[6];
    const float* btop  = (const float*)d_in[7];
    const int E = in_sizes[2] / 2;

    char* ws = (char*)d_ws;
    u16*   embT   = (u16*)  (ws + 0);           // 4 MiB   [256][8192] bf16
    float* Cacc   = (float*)(ws + 4194304);     // 32 MiB  KS slabs [8192][256] f32
    float* emb1   = (float*)(ws + 37748736);    // 8 MiB   [8192][256] f32
    u16*   xbf    = (u16*)  (ws + 46137344);    // 4 MiB   [8192][256] bf16
    u16*   WT     = (u16*)  (ws + 50331648);    // 128 KiB [256][256] bf16
    float* rsb    = (float*)(ws + 50462720);    // 128 KiB KS slabs [8192] f32
    float* dinv   = (float*)(ws + 50593792);    // 32 KiB
    int*   counts = (int*)  (ws + 50626560);    // 32 KiB
    int*   offs   = (int*)  (ws + 50659328);    // 36 KiB (NN+1 ints)
    int*   cursor = (int*)  (ws + 50696192);    // 32 KiB
    int*   csr    = (int*)  (ws + 50728960);    // 512 KiB

    const dim3 blk(256);
    const dim3 gDense(128, 1, KS), gGcn(128, 1, 1);
    const dim3 gE((E + 255) / 256), gG(NN / 4);

    // embT = bf16(emb0)^T
    tc_k<<<dim3(128, 4), blk, 0, stream>>>(emb0, embT, NN, DD);

    // ---- level 0 (slab split-K: no memset, no atomics)
    gemm_k<true, true><<<gDense, blk, 0, stream>>>(A, NN, embT, NN, Cacc, rsb, NN / KS);
    norm0_k<<<dim3(128, 4), blk, 0, stream>>>(Cacc, rsb, emb0, emb1, embT);

    // ---- level 1
    gemm_k<true, true><<<gDense, blk, 0, stream>>>(A + (size_t)NN * NN, NN, embT, NN, Cacc, rsb, NN / KS);
    norm1_k<<<dim3(2048), blk, 0, stream>>>(Cacc, rsb, emb1, xbf);

    // ---- GCN layer 1 (same_level)
    tc_k<<<dim3(4, 4), blk, 0, stream>>>(Wsame, WT, DD, DD);
    hipMemsetAsync(counts, 0, 32768, stream);
    count_k<<<gE, blk, 0, stream>>>(eiS + E, E, counts);
    scan_k<<<dim3(1), dim3(1024), 0, stream>>>(counts, offs, cursor, dinv);
    fill_k<<<gE, blk, 0, stream>>>(eiS, eiS + E, E, cursor, csr);
    gemm_k<false, false><<<gGcn, blk, 0, stream>>>(xbf, DD, WT, DD, Cacc, nullptr, 256);
    gather_k<<<gG, blk, 0, stream>>>(Cacc, offs, csr, dinv, bsame, xbf, nullptr);

    // ---- GCN layer 2 (up2down)
    tc_k<<<dim3(4, 4), blk, 0, stream>>>(Wtop, WT, DD, DD);
    hipMemsetAsync(counts, 0, 32768, stream);
    count_k<<<gE, blk, 0, stream>>>(eiU + E, E, counts);
    scan_k<<<dim3(1), dim3(1024), 0, stream>>>(counts, offs, cursor, dinv);
    fill_k<<<gE, blk, 0, stream>>>(eiU, eiU + E, E, cursor, csr);
    gemm_k<false, false><<<gGcn, blk, 0, stream>>>(xbf, DD, WT, DD, Cacc, nullptr, 256);
    gather_k<<<gG, blk, 0, stream>>>(Cacc, offs, csr, dinv, btop, nullptr, (float*)d_out);
}

// Round 3
// 925.461 us; speedup vs baseline: 1.1624x; 1.0716x over previous
//
#include <hip/hip_runtime.h>
#include <cstdint>

#define NN 8192
#define DD 256
#define KS 4   // k-splits for the dense levels

typedef unsigned short u16;
typedef __bf16 bf16x8 __attribute__((ext_vector_type(8)));
typedef float f32x4 __attribute__((ext_vector_type(4)));

__device__ __forceinline__ u16 f2bf(float f) {
    union { float f; unsigned u; } c; c.f = f;
    unsigned u = c.u;
    return (u16)((u + 0x7FFFu + ((u >> 16) & 1u)) >> 16);   // RNE
}

__device__ __forceinline__ void cvt_store8(f32x4 a, f32x4 b, u16* dst) {
    union { u16 u[8]; uint4 v; } pk;
    pk.u[0] = f2bf(a[0]); pk.u[1] = f2bf(a[1]);
    pk.u[2] = f2bf(a[2]); pk.u[3] = f2bf(a[3]);
    pk.u[4] = f2bf(b[0]); pk.u[5] = f2bf(b[1]);
    pk.u[6] = f2bf(b[2]); pk.u[7] = f2bf(b[3]);
    *(uint4*)dst = pk.v;
}

// ---------------------------------------------------------------------------
// GEMM: C[M x 256] = A[M x K] * B[K x 256], B given transposed (BT[n][k], bf16).
// A fp32 (AF32=1, converted in-kernel) or bf16 (AF32=0).
// Tile 64(m) x 256(n) x 32(k-step); 4 waves; wave w owns n in [64w, 64w+64).
// 2-phase software pipeline: stage(t+1) issued BEFORE compute(t), double-
// buffered LDS, one barrier per k-step — loads land under the MFMA phase.
// Pipeline hazard audit: buffer b is read in step t (LDS reads complete at the
// step-t barrier, which drains lgkm+vm for every wave); writes to b are issued
// in step t+1 strictly after that barrier. One barrier per step suffices.
// Split-K: block z writes slab C + z*NN*DD (no atomics); reduction fused into
// the norm kernels. ROWSUM: wave 0 accumulates rowsum(A) via ones-column B.
// ---------------------------------------------------------------------------
template<bool AF32, bool ROWSUM>
__global__ __launch_bounds__(256, 2)
void gemm_k(const void* __restrict__ Ap, long ldA,
            const u16* __restrict__ BT, long ldBT,
            float* __restrict__ C, float* __restrict__ rs, int kPer)
{
    __shared__ __align__(16) u16 As[2][64 * 32];
    __shared__ __align__(16) u16 Bs[2][256 * 32];

    const int tid  = threadIdx.x;
    const int lane = tid & 63;
    const int wave = tid >> 6;       // 0..3
    const int r    = lane & 15;
    const int q    = lane >> 4;
    const long m0  = (long)blockIdx.x * 64;
    const long k0  = (long)blockIdx.z * kPer;
    float* __restrict__ Cs = C + (long)blockIdx.z * ((long)NN * DD);

    f32x4 acc[4][4] = {};
    f32x4 racc[4]   = {};
    bf16x8 ones;
    if constexpr (ROWSUM) {
        union { bf16x8 v; u16 u[8]; } cv;
        u16 pat = (r == 0) ? (u16)0x3F80 : (u16)0;   // 1.0 in n-col 0
        #pragma unroll
        for (int j = 0; j < 8; ++j) cv.u[j] = pat;
        ones = cv.v;
    }

    // B staging: wave loads groups 4w..4w+3 (rows wave*64 + g2*16 + r)
    const u16* bBase = BT + (long)(wave * 64 + r) * ldBT + k0 + q * 8;
    // A staging (AF32): thread t handles row t>>2, k-octet t&3 (8 fp32 -> 8 bf16)
    const int arow = tid >> 2;
    const int kq8  = tid & 3;
    const float* aBaseF = AF32 ? ((const float*)Ap + (m0 + arow) * ldA + k0 + kq8 * 8) : nullptr;
    u16* const aDst0 = &As[0][(arow >> 4) * 512 + (kq8 * 16 + (arow & 15)) * 8];
    u16* const aDst1 = &As[1][(arow >> 4) * 512 + (kq8 * 16 + (arow & 15)) * 8];
    // A staging (bf16): wave loads group `wave` via global_load_lds
    const u16* aBaseH = AF32 ? nullptr
                             : ((const u16*)Ap + (m0 + wave * 16 + r) * ldA + k0 + q * 8);
    const int nsteps = kPer >> 5;

#define STAGE_B(t, buf) do {                                                      \
    const long koff_ = (long)(t) << 5;                                            \
    _Pragma("unroll")                                                             \
    for (int g2_ = 0; g2_ < 4; ++g2_)                                             \
        __builtin_amdgcn_global_load_lds(                                         \
            (const __attribute__((address_space(1))) void*)(bBase + (long)g2_ * 16 * ldBT + koff_), \
            (__attribute__((address_space(3))) void*)(&Bs[buf][(wave * 4 + g2_) * 512 + lane * 8]), \
            16, 0, 0);                                                            \
  } while (0)

#define STAGE_AH(t, buf)                                                          \
    __builtin_amdgcn_global_load_lds(                                             \
        (const __attribute__((address_space(1))) void*)(aBaseH + ((long)(t) << 5)), \
        (__attribute__((address_space(3))) void*)(&As[buf][wave * 512 + lane * 8]), \
        16, 0, 0)

    // ---- prologue: stage tile 0 into buffer 0
    STAGE_B(0, 0);
    if constexpr (AF32) {
        f32x4 p0 = __builtin_nontemporal_load((const f32x4*)aBaseF);
        f32x4 p1 = __builtin_nontemporal_load((const f32x4*)(aBaseF + 4));
        cvt_store8(p0, p1, aDst0);
    } else {
        STAGE_AH(0, 0);
    }
    __syncthreads();

    for (int t = 0; t < nsteps; ++t) {
        const int cur = t & 1, nxt = cur ^ 1;
        const bool more = (t + 1 < nsteps);
        f32x4 na0, na1;
        if (more) {
            STAGE_B(t + 1, nxt);                    // async, lands during compute
            if constexpr (AF32) {
                const float* ap = aBaseF + ((long)(t + 1) << 5);
                na0 = __builtin_nontemporal_load((const f32x4*)ap);
                na1 = __builtin_nontemporal_load((const f32x4*)(ap + 4));
            } else {
                STAGE_AH(t + 1, nxt);
            }
        }
        bf16x8 af[4], bfr[4];
        #pragma unroll
        for (int i = 0; i < 4; ++i) {
            af[i]  = *(const bf16x8*)(&As[cur][i * 512 + lane * 8]);
            bfr[i] = *(const bf16x8*)(&Bs[cur][(wave * 4 + i) * 512 + lane * 8]);
        }
        #pragma unroll
        for (int i = 0; i < 4; ++i)
            #pragma unroll
            for (int j = 0; j < 4; ++j)
                acc[i][j] = __builtin_amdgcn_mfma_f32_16x16x32_bf16(af[i], bfr[j], acc[i][j], 0, 0, 0);
        if constexpr (ROWSUM) {
            if (wave == 0) {
                #pragma unroll
                for (int i = 0; i < 4; ++i)
                    racc[i] = __builtin_amdgcn_mfma_f32_16x16x32_bf16(af[i], ones, racc[i], 0, 0, 0);
            }
        }
        if constexpr (AF32) {
            if (more) cvt_store8(na0, na1, (nxt ? aDst1 : aDst0));  // waits its loads here
        }
        __syncthreads();
    }
#undef STAGE_B
#undef STAGE_AH

    // epilogue: C/D layout col = lane&15, row = (lane>>4)*4 + reg
    #pragma unroll
    for (int i = 0; i < 4; ++i) {
        const long rowb = m0 + i * 16 + q * 4;
        #pragma unroll
        for (int j = 0; j < 4; ++j) {
            const long col = wave * 64 + j * 16 + r;
            #pragma unroll
            for (int rr2 = 0; rr2 < 4; ++rr2)
                Cs[(rowb + rr2) * DD + col] = acc[i][j][rr2];
        }
        if constexpr (ROWSUM) {
            if (wave == 0 && r == 0) {
                #pragma unroll
                for (int rr2 = 0; rr2 < 4; ++rr2)
                    rs[(long)blockIdx.z * NN + rowb + rr2] = racc[i][rr2];
            }
        }
    }
}

// ---------------------------------------------------------------------------
// transpose-convert: src fp32 [R][C] -> dst bf16 [C][R]. 64x64 tiles.
// ---------------------------------------------------------------------------
__global__ __launch_bounds__(256)
void tc_k(const float* __restrict__ src, u16* __restrict__ dst, int R, int C)
{
    __shared__ u16 t[64][72];
    const int tid = threadIdx.x;
    const int rr = tid >> 2;
    const int cc = (tid & 3) << 4;
    const long r0 = (long)blockIdx.x * 64;
    const long c0 = (long)blockIdx.y * 64;
    const float* sp = src + (r0 + rr) * C + c0 + cc;
    #pragma unroll
    for (int j = 0; j < 16; ++j) t[cc + j][rr] = f2bf(sp[j]);
    __syncthreads();
    u16* dp = dst + (c0 + rr) * (long)R + r0 + cc;
    #pragma unroll
    for (int j = 0; j < 16; ++j) dp[j] = t[rr][cc + j];
}

// both 256x256 weight transposes in one launch (z selects)
__global__ __launch_bounds__(256)
void tcw_k(const float* __restrict__ w0, const float* __restrict__ w1,
           u16* __restrict__ dst)
{
    __shared__ u16 t[64][72];
    const float* src = blockIdx.z ? w1 : w0;
    u16* d = dst + (size_t)blockIdx.z * DD * DD;
    const int tid = threadIdx.x;
    const int rr = tid >> 2;
    const int cc = (tid & 3) << 4;
    const long r0 = (long)blockIdx.x * 64;
    const long c0 = (long)blockIdx.y * 64;
    const float* sp = src + (r0 + rr) * DD + c0 + cc;
    #pragma unroll
    for (int j = 0; j < 16; ++j) t[cc + j][rr] = f2bf(sp[j]);
    __syncthreads();
    u16* dp = d + (c0 + rr) * (long)DD + r0 + cc;
    #pragma unroll
    for (int j = 0; j < 16; ++j) dp[j] = t[rr][cc + j];
}

// ---------------------------------------------------------------------------
// norm0: v = (resid + sum_s Cacc[s]) * 1/(sum_s rs[s]+1); write outF fp32
// [N][256] AND outT bf16 [256][N] (transposed). 64x64 tiles.
// ---------------------------------------------------------------------------
__global__ __launch_bounds__(256)
void norm0_k(const float* __restrict__ Cacc, const float* __restrict__ rs,
             const float* __restrict__ resid,
             float* __restrict__ outF, u16* __restrict__ outT)
{
    __shared__ u16 t[64][72];
    const int tid = threadIdx.x;
    const int rr = tid >> 2;
    const int cc = (tid & 3) << 4;
    const long i0 = (long)blockIdx.x * 64;
    const int  n0 = blockIdx.y * 64;
    const long i  = i0 + rr;
    const float rsum = rs[i] + rs[NN + i] + rs[2 * NN + i] + rs[3 * NN + i];
    const float scale = 1.0f / (rsum + 1.0f);
    const float* c0p = Cacc + i * DD + n0 + cc;
    const float* rp  = resid + i * DD + n0 + cc;
    float* fp = outF + i * DD + n0 + cc;
    const long slab = (long)NN * DD;
    #pragma unroll
    for (int j = 0; j < 16; ++j) {
        float v = rp[j] + c0p[j] + c0p[j + slab] + c0p[j + 2 * slab] + c0p[j + 3 * slab];
        v *= scale;
        fp[j] = v;
        t[cc + j][rr] = f2bf(v);
    }
    __syncthreads();
    u16* op = outT + (long)(n0 + rr) * NN + i0 + cc;
    #pragma unroll
    for (int j = 0; j < 16; ++j) op[j] = t[rr][cc + j];
}

// ---------------------------------------------------------------------------
// norm1: v = (resid + sum_s Cacc[s]) * 1/(sum_s rs[s]+1); write bf16 row-major
// [N][256]. grid 2048 x 256thr, 4 elems/thread.
// ---------------------------------------------------------------------------
__global__ __launch_bounds__(256)
void norm1_k(const float* __restrict__ Cacc, const float* __restrict__ rs,
             const float* __restrict__ resid, u16* __restrict__ outR)
{
    const long g = ((long)blockIdx.x * 256 + threadIdx.x) * 4;
    const long row = g >> 8;
    const float rsum = rs[row] + rs[NN + row] + rs[2 * NN + row] + rs[3 * NN + row];
    const float scale = 1.0f / (rsum + 1.0f);
    const long slab = (long)NN * DD;
    const float4 c0 = *(const float4*)(Cacc + g);
    const float4 c1 = *(const float4*)(Cacc + g + slab);
    const float4 c2 = *(const float4*)(Cacc + g + 2 * slab);
    const float4 c3 = *(const float4*)(Cacc + g + 3 * slab);
    const float4 rv = *(const float4*)(resid + g);
    u16* op = outR + g;
    op[0] = f2bf((rv.x + c0.x + c1.x + c2.x + c3.x) * scale);
    op[1] = f2bf((rv.y + c0.y + c1.y + c2.y + c3.y) * scale);
    op[2] = f2bf((rv.z + c0.z + c1.z + c2.z + c3.z) * scale);
    op[3] = f2bf((rv.w + c0.w + c1.w + c2.w + c3.w) * scale);
}

// ---------------------------------------------------------------------------
// GCN helpers: both edge lists handled in one launch (grid picks the list)
// ---------------------------------------------------------------------------
__global__ __launch_bounds__(256)
void count2_k(const int* __restrict__ dS, const int* __restrict__ dU, int E,
              int* __restrict__ counts) {
    const int e = blockIdx.x * 256 + threadIdx.x;
    const int* d = blockIdx.y ? dU : dS;
    if (e < E) atomicAdd(counts + blockIdx.y * NN + d[e], 1);
}

// exclusive scan of 8192 counts per list; one block per list, 1024 threads,
// wave-shuffle scan.
__global__ __launch_bounds__(1024)
void scan2_k(const int* __restrict__ counts, int* __restrict__ offs,
             int* __restrict__ cursor, float* __restrict__ dinv) {
    const int p = blockIdx.x;
    const int* cnt = counts + p * NN;
    int* off   = offs + p * (NN + 1);
    int* curp  = cursor + p * NN;
    float* dv  = dinv + p * NN;

    __shared__ int wpre[17];
    __shared__ int sbase;
    const int tid  = threadIdx.x;
    const int lane = tid & 63;
    const int wid  = tid >> 6;          // 0..15
    if (tid == 0) { sbase = 0; wpre[0] = 0; }
    __syncthreads();
    for (int base = 0; base < NN; base += 1024) {
        const int c = cnt[base + tid];
        dv[base + tid] = 1.0f / sqrtf((float)c + 1.0f);
        int x = c;                       // inclusive wave scan
        #pragma unroll
        for (int d = 1; d < 64; d <<= 1) {
            int y = __shfl_up(x, d, 64);
            if (lane >= d) x += y;
        }
        if (lane == 63) wpre[wid + 1] = x;
        __syncthreads();
        if (wid == 0) {                  // scan the 16 wave sums
            int w = (lane < 16) ? wpre[lane + 1] : 0;
            #pragma unroll
            for (int d = 1; d < 16; d <<= 1) {
                int y = __shfl_up(w, d, 64);
                if (lane >= d) w += y;
            }
            if (lane < 16) wpre[lane + 1] = w;
        }
        __syncthreads();
        const int tot  = wpre[16];       // read BEFORE the next barrier
        const int excl = sbase + wpre[wid] + (x - c);
        off[base + tid]  = excl;
        curp[base + tid] = excl;
        __syncthreads();                 // all wpre/sbase reads done
        if (tid == 0) sbase += tot;
    }
    if (tid == 0) off[NN] = sbase;
}

__global__ __launch_bounds__(256)
void fill2_k(const int* __restrict__ eiS, const int* __restrict__ eiU, int E,
             int* __restrict__ cursor, int* __restrict__ csr) {
    const int e = blockIdx.x * 256 + threadIdx.x;
    const int p = blockIdx.y;
    const int* src = p ? eiU : eiS;
    const int* dst = src + E;
    if (e < E) {
        int pos = atomicAdd(cursor + p * NN + dst[e], 1);
        csr[p * ((1 << 17) + NN) + pos] = src[e];
    }
}

// ---------------------------------------------------------------------------
// gather: out[i] = b + dinv[i]^2*h[i] + sum_{e:dst=i} dinv[i]*dinv[src]*h[src]
// one wave per node, lane owns 4 features. csr indices + weights prefetched
// lane-parallel (off the critical chain), then 4 independent row loads/step.
// ---------------------------------------------------------------------------
__global__ __launch_bounds__(256)
void gather_k(const float* __restrict__ h,
              const int* __restrict__ offs,
              const int* __restrict__ csr,
              const float* __restrict__ dinv,
              const float* __restrict__ bias,
              u16* __restrict__ outBF,
              float* __restrict__ outF)
{
    const int node = blockIdx.x * 4 + (threadIdx.x >> 6);
    const int lane = threadIdx.x & 63;
    const float di = dinv[node];
    const float4 hs = ((const float4*)(h + (long)node * DD))[lane];
    const float s0 = di * di;
    float4 acc;
    acc.x = hs.x * s0; acc.y = hs.y * s0; acc.z = hs.z * s0; acc.w = hs.w * s0;

    const int b0 = offs[node], b1 = offs[node + 1];
    for (int base = b0; base < b1; base += 64) {
        const int nb = (b1 - base < 64) ? (b1 - base) : 64;
        int   sidx = node;
        float wv   = 0.0f;
        if (lane < nb) {                       // prefetch indices + weights
            sidx = csr[base + lane];
            wv   = di * dinv[sidx];
        }
        int e = 0;
        for (; e + 4 <= nb; e += 4) {
            const int   i0 = __shfl(sidx, e),     i1 = __shfl(sidx, e + 1);
            const int   i2 = __shfl(sidx, e + 2), i3 = __shfl(sidx, e + 3);
            const float w0 = __shfl(wv, e),       w1 = __shfl(wv, e + 1);
            const float w2 = __shfl(wv, e + 2),   w3 = __shfl(wv, e + 3);
            const float4 x0 = ((const float4*)(h + (long)i0 * DD))[lane];
            const float4 x1 = ((const float4*)(h + (long)i1 * DD))[lane];
            const float4 x2 = ((const float4*)(h + (long)i2 * DD))[lane];
            const float4 x3 = ((const float4*)(h + (long)i3 * DD))[lane];
            acc.x += w0 * x0.x + w1 * x1.x + w2 * x2.x + w3 * x3.x;
            acc.y += w0 * x0.y + w1 * x1.y + w2 * x2.y + w3 * x3.y;
            acc.z += w0 * x0.z + w1 * x1.z + w2 * x2.z + w3 * x3.z;
            acc.w += w0 * x0.w + w1 * x1.w + w2 * x2.w + w3 * x3.w;
        }
        for (; e < nb; ++e) {
            const int   s = __shfl(sidx, e);
            const float w = __shfl(wv, e);
            const float4 x = ((const float4*)(h + (long)s * DD))[lane];
            acc.x += w * x.x; acc.y += w * x.y; acc.z += w * x.z; acc.w += w * x.w;
        }
    }
    const float4 bv = ((const float4*)bias)[lane];
    acc.x += bv.x; acc.y += bv.y; acc.z += bv.z; acc.w += bv.w;

    if (outF) {
        ((float4*)(outF + (long)node * DD))[lane] = acc;
    } else {
        u16* op = outBF + (long)node * DD + lane * 4;
        op[0] = f2bf(acc.x); op[1] = f2bf(acc.y);
        op[2] = f2bf(acc.z); op[3] = f2bf(acc.w);
    }
}

// ---------------------------------------------------------------------------
extern "C" void kernel_launch(void* const* d_in, const int* in_sizes, int n_in,
                              void* d_out, int out_size, void* d_ws, size_t ws_size,
                              hipStream_t stream)
{
    (void)n_in; (void)out_size; (void)ws_size;
    const float* emb0  = (const float*)d_in[0];
    const float* A     = (const float*)d_in[1];
    const int*   eiS   = (const int*)d_in[2];
    const int*   eiU   = (const int*)d_in[3];
    const float* Wsame = (const float*)d_in[4];
    const float* bsame = (const float*)d_in[5];
    const float* Wtop  = (const float*)d_in[6];
    const float* btop  = (const float*)d_in[7];
    const int E = in_sizes[2] / 2;
    const int CSRSZ = (1 << 17) + NN;   // per-list csr capacity (E + slack)

    char* ws = (char*)d_ws;
    u16*   embT   = (u16*)  (ws + 0);           // 4 MiB   [256][8192] bf16
    float* Cacc   = (float*)(ws + 4194304);     // 32 MiB  KS slabs [8192][256] f32
    float* emb1   = (float*)(ws + 37748736);    // 8 MiB   [8192][256] f32
    u16*   xbf    = (u16*)  (ws + 46137344);    // 4 MiB   [8192][256] bf16
    u16*   WT     = (u16*)  (ws + 50331648);    // 256 KiB 2x [256][256] bf16
    float* rsb    = (float*)(ws + 50593792);    // 128 KiB KS slabs [8192] f32
    float* dinv2  = (float*)(ws + 50724864);    // 64 KiB  2x [8192]
    int*   counts = (int*)  (ws + 50790400);    // 64 KiB  2x [8192]
    int*   offs2  = (int*)  (ws + 50855936);    // 2x (NN+1) ints
    int*   cursor = (int*)  (ws + 50921488);    // 64 KiB  2x [8192]
    int*   csr2   = (int*)  (ws + 50987024);    // 2x CSRSZ ints

    const dim3 blk(256);
    const dim3 gDense(128, 1, KS), gGcn(128, 1, 1);
    const dim3 gE2((E + 255) / 256, 2), gG(NN / 4);

    // embT = bf16(emb0)^T ; weight transposes ; CSR build for both GCN layers
    tc_k<<<dim3(128, 4), blk, 0, stream>>>(emb0, embT, NN, DD);
    tcw_k<<<dim3(4, 4, 2), blk, 0, stream>>>(Wsame, Wtop, WT);
    hipMemsetAsync(counts, 0, 65536, stream);
    count2_k<<<gE2, blk, 0, stream>>>(eiS + E, eiU + E, E, counts);
    scan2_k<<<dim3(2), dim3(1024), 0, stream>>>(counts, offs2, cursor, dinv2);
    fill2_k<<<gE2, blk, 0, stream>>>(eiS, eiU, E, cursor, csr2);

    // ---- level 0 (slab split-K: no memset, no atomics)
    gemm_k<true, true><<<gDense, blk, 0, stream>>>(A, NN, embT, NN, Cacc, rsb, NN / KS);
    norm0_k<<<dim3(128, 4), blk, 0, stream>>>(Cacc, rsb, emb0, emb1, embT);

    // ---- level 1
    gemm_k<true, true><<<gDense, blk, 0, stream>>>(A + (size_t)NN * NN, NN, embT, NN, Cacc, rsb, NN / KS);
    norm1_k<<<dim3(2048), blk, 0, stream>>>(Cacc, rsb, emb1, xbf);

    // ---- GCN layer 1 (same_level)
    gemm_k<false, false><<<gGcn, blk, 0, stream>>>(xbf, DD, WT, DD, Cacc, nullptr, 256);
    gather_k<<<gG, blk, 0, stream>>>(Cacc, offs2, csr2, dinv2, bsame, xbf, nullptr);

    // ---- GCN layer 2 (up2down)
    gemm_k<false, false><<<gGcn, blk, 0, stream>>>(xbf, DD, WT + DD * DD, DD, Cacc, nullptr, 256);
    gather_k<<<gG, blk, 0, stream>>>(Cacc, offs2 + (NN + 1), csr2 + CSRSZ,
                                     dinv2 + NN, btop, nullptr, (float*)d_out);
}